// Round 9
// baseline (654.609 us; speedup 1.0000x reference)
//
#include <hip/hip_runtime.h>
#include <hip/hip_bf16.h>
#include <stdint.h>

// Problem dims (fixed by the reference)
constexpr int kB = 32;
constexpr int kS = 1024;
constexpr int kDin = 1024;
constexpr int kDout = 4096;
constexpr int kRank = 16;
constexpr int kNAdapt = 8;
constexpr int kM = kB * kS;     // 32768 rows
constexpr float kScale = 2.0f;  // alpha/rank = 32/16

typedef __attribute__((ext_vector_type(4))) float f32x4;
typedef __attribute__((ext_vector_type(8))) short s16x8;
typedef __attribute__((ext_vector_type(8))) unsigned short u16x8;
typedef __attribute__((ext_vector_type(4))) unsigned short u16x4;

__device__ __forceinline__ unsigned short f2bf(float f) {
  union { float f; uint32_t u; } x; x.f = f;
  uint32_t u = x.u;
  u += 0x7fffu + ((u >> 16) & 1u);   // round-to-nearest-even
  return (unsigned short)(u >> 16);
}

// ---------- Fused prep kernel: weff blocks (bid<8192) + cast grid-stride ----------
constexpr int kWeffBlocks = kNAdapt * (kDin / 64) * (kDout / 64);   // 8192
constexpr int kCastBlocks = 2048;

__global__ __launch_bounds__(256) void prep_kernel(
    const float* __restrict__ h, unsigned short* __restrict__ hout,
    const float* __restrict__ W, const float* __restrict__ la,
    const float* __restrict__ lb, unsigned short* __restrict__ weff) {
  __shared__ float Wt[64][68];
  __shared__ float At[64][20];
  __shared__ float Bt[16][68];
  int bid = blockIdx.x;
  int t = threadIdx.x;
  if (bid >= kWeffBlocks) {
    int cb = bid - kWeffBlocks;
    size_t base = (size_t)cb * 256 + t;
    constexpr size_t stride = (size_t)kCastBlocks * 256;
    constexpr size_t total8 = (size_t)kM * kDin / 8;
#pragma unroll
    for (int p = 0; p < 8; ++p) {
      size_t i = base + p * stride;
      if (i < total8) {
        const f32x4* src = reinterpret_cast<const f32x4*>(h) + i * 2;
        f32x4 v0 = src[0], v1 = src[1];
        u16x8 r;
        r[0] = f2bf(v0[0]); r[1] = f2bf(v0[1]); r[2] = f2bf(v0[2]); r[3] = f2bf(v0[3]);
        r[4] = f2bf(v1[0]); r[5] = f2bf(v1[1]); r[6] = f2bf(v1[2]); r[7] = f2bf(v1[3]);
        *reinterpret_cast<u16x8*>(hout + i * 8) = r;
      }
    }
    return;
  }
  int e = bid & 7;
  int rem = bid >> 3;
  int dt = rem >> 6;
  int ot = rem & 63;
  int d0 = dt * 64, o0 = ot * 64;
  {
    int r = t >> 4;
    int c = (t & 15) * 4;
    const float* wp = W + (size_t)(d0 + r) * kDout + o0 + c;
#pragma unroll
    for (int p = 0; p < 4; ++p) {
      f32x4 v = *reinterpret_cast<const f32x4*>(wp + (size_t)p * 16 * kDout);
      *reinterpret_cast<f32x4*>(&Wt[p * 16 + r][c]) = v;
    }
  }
  {
    int d = t >> 2, r4 = (t & 3) * 4;
    f32x4 v = *reinterpret_cast<const f32x4*>(la + ((size_t)e * kDin + d0 + d) * kRank + r4);
    *reinterpret_cast<f32x4*>(&At[d][r4]) = v;
  }
  {
    int r = t >> 4, c = (t & 15) * 4;
    f32x4 v = *reinterpret_cast<const f32x4*>(lb + ((size_t)e * kRank + r) * kDout + o0 + c);
    *reinterpret_cast<f32x4*>(&Bt[r][c]) = v;
  }
  __syncthreads();
  int ol_base = t >> 4;
  int dl = (t & 15) * 4;
  f32x4 areg[4][4];
#pragma unroll
  for (int j = 0; j < 4; ++j)
#pragma unroll
    for (int q = 0; q < 4; ++q)
      areg[j][q] = *reinterpret_cast<const f32x4*>(&At[dl + j][q * 4]);
#pragma unroll
  for (int p = 0; p < 4; ++p) {
    int ol = p * 16 + ol_base;
    float bv[kRank];
#pragma unroll
    for (int r = 0; r < kRank; ++r) bv[r] = Bt[r][ol];
    u16x4 r4;
#pragma unroll
    for (int j = 0; j < 4; ++j) {
      float acc = 0.f;
#pragma unroll
      for (int q = 0; q < 4; ++q)
        acc += areg[j][q][0] * bv[q * 4 + 0] + areg[j][q][1] * bv[q * 4 + 1] +
               areg[j][q][2] * bv[q * 4 + 2] + areg[j][q][3] * bv[q * 4 + 3];
      r4[j] = f2bf(Wt[dl + j][ol] + kScale * acc);
    }
    *reinterpret_cast<u16x4*>(weff + ((size_t)e * kDout + o0 + ol) * kDin + d0 + dl) = r4;
  }
}

// ---------- GEMM: 256x256, 16 waves (64x64 each, 4 waves/SIMD), single
// barrier per K-tile, A tribuf + B dbuf, counted VMC(2). Per-wave acc = 64
// regs -> launch_bounds(1024,4) caps VGPR at 128 -> 4 waves/SIMD TLP.
constexpr int BM = 256, BN = 256, BK = 64;
constexpr int MT2 = kM / BM;      // 128
constexpr int NT2 = kDout / BN;   // 16
constexpr int NWG2 = MT2 * NT2;   // 2048

__device__ __forceinline__ void gload16(const unsigned short* g, unsigned short* l) {
  __builtin_amdgcn_global_load_lds((const __attribute__((address_space(1))) void*)g,
                                   (__attribute__((address_space(3))) void*)l, 16, 0, 0);
}

// LDS elem layout: A slot s in [0,3): s*16384; B slot s in [0,2): 49152+s*16384
// logical (row r, el c) at r*64 + (c ^ ((r&7)<<3)); source pre-swizzled.
// 1024 threads: one gload covers 128 rows (t>>3), 16B col (t&7)*16.
#define STG_A(s, kk) do { \
  gload16(gA + (kk) * 64, ldst + (s) * 16384); \
  gload16(gA + (size_t)128 * kDin + (kk) * 64, ldst + (s) * 16384 + 8192); \
} while (0)
#define STG_B(s, kk) do { \
  gload16(gB + (kk) * 64, ldst + 49152 + (s) * 16384); \
  gload16(gB + (size_t)128 * kDin + (kk) * 64, ldst + 49152 + (s) * 16384 + 8192); \
} while (0)

#define RD_A2(ah, s) do { _Pragma("unroll") for (int ii = 0; ii < 2; ++ii) { \
  a[ii][0] = *(const s16x8*)&lds[(s) * 16384 + aRow + ((ah) * 2 + ii) * 1024 + e0]; \
  a[ii][1] = *(const s16x8*)&lds[(s) * 16384 + aRow + ((ah) * 2 + ii) * 1024 + e1]; } } while (0)
#define RD_B2(nh, breg, s) do { _Pragma("unroll") for (int jj = 0; jj < 2; ++jj) { \
  breg[jj][0] = *(const s16x8*)&lds[49152 + (s) * 16384 + bRow + ((nh) * 2 + jj) * 1024 + e0]; \
  breg[jj][1] = *(const s16x8*)&lds[49152 + (s) * 16384 + bRow + ((nh) * 2 + jj) * 1024 + e1]; } } while (0)

// 8 MFMA: a(2 frag-rows) x breg(2 frag-cols) x 2 kc -> acc[ah*2+ii][nh*2+jj]
#define MMQ2(ah, nh, breg) do { \
  _Pragma("unroll") for (int ii = 0; ii < 2; ++ii) \
  _Pragma("unroll") for (int jj = 0; jj < 2; ++jj) { \
    acc[(ah) * 2 + ii][(nh) * 2 + jj] = __builtin_amdgcn_mfma_f32_16x16x32_bf16( \
        a[ii][0], breg[jj][0], acc[(ah) * 2 + ii][(nh) * 2 + jj], 0, 0, 0); \
    acc[(ah) * 2 + ii][(nh) * 2 + jj] = __builtin_amdgcn_mfma_f32_16x16x32_bf16( \
        a[ii][1], breg[jj][1], acc[(ah) * 2 + ii][(nh) * 2 + jj], 0, 0, 0); } \
} while (0)

#define VMC(n) asm volatile("s_waitcnt vmcnt(" #n ")" ::: "memory")

__global__ __launch_bounds__(1024, 4) void gemm256_kernel(
    const unsigned short* __restrict__ Ab,    // [M][K] bf16
    const unsigned short* __restrict__ Weff,  // [NA][N][K] bf16
    const float* __restrict__ bias,
    const int* __restrict__ aids,
    float* __restrict__ out) {
  __shared__ unsigned short lds[81920];   // 160 KiB: A[3] + B[2] slots
  int bid = blockIdx.x;
  int swz = (bid & 7) * (NWG2 / 8) + (bid >> 3);   // XCD-aware, bijective
  int mt = swz >> 4, nt = swz & 15;
  int aid = aids[mt >> 2];   // BM=256 divides S=1024: one sample per M-tile
  const unsigned short* Aptr = Ab + (size_t)mt * BM * kDin;
  const unsigned short* Bptr = Weff + ((size_t)aid * kDout + (size_t)nt * BN) * kDin;

  int t = threadIdx.x;
  int l = t & 63;
  int w = t >> 6;        // 0..15
  int wm = w >> 2;       // 0..3 (M), owns rows wm*64..+63
  int wn = w & 3;        // 0..3 (N), owns cols wn*64..+63

  // staging: thread t covers rows (t>>3) and (t>>3)+128, 16B col (t&7);
  // global source col pre-swizzled so LDS stays linear (rule #21)
  int srcColEl = ((t & 7) * 8) ^ (((t >> 3) & 7) << 3);
  const unsigned short* gA = Aptr + (size_t)(t >> 3) * kDin + srcColEl;
  const unsigned short* gB = Bptr + (size_t)(t >> 3) * kDin + srcColEl;
  unsigned short* ldst = lds + t * 8;

  // fragment-read addressing (element units)
  int xmEl = (l & 7) << 3;
  int e0 = (((l >> 4) * 8) ^ xmEl);
  int e1 = e0 ^ 32;
  int aRow = (wm * 64 + (l & 15)) * 64;
  int bRow = (wn * 64 + (l & 15)) * 64;

  f32x4 acc[4][4];   // 64 regs
#pragma unroll
  for (int m = 0; m < 4; ++m)
#pragma unroll
    for (int n = 0; n < 4; ++n) acc[m][n] = f32x4{0.f, 0.f, 0.f, 0.f};
  s16x8 a[2][2], b0[2][2], b1[2][2];

  // prologue FIFO: [A0(2), B0(2), A1(2)]
  STG_A(0, 0); STG_B(0, 0); STG_A(1, 1);

#pragma unroll
  for (int kt = 0; kt < 16; ++kt) {
    const int sa = kt % 3;          // A slot being read
    const int sb = kt & 1;          // B slot being read
    if (kt < 15) { VMC(2); } else { VMC(0); }   // L(kt) landed; A(kt+1) may fly
    __builtin_amdgcn_s_barrier();
    __builtin_amdgcn_sched_barrier(0);
    if (kt < 15) STG_B((kt + 1) & 1, kt + 1);   // slot last read kt-1: safe
    // ---- body: no fences; compiler interleaves ds_read/MFMA ----
    RD_A2(0, sa);
    RD_B2(0, b0, sb); RD_B2(1, b1, sb);
    __builtin_amdgcn_s_setprio(1);
    MMQ2(0, 0, b0); MMQ2(0, 1, b1);
    RD_A2(1, sa);
    MMQ2(1, 0, b0); MMQ2(1, 1, b1);
    __builtin_amdgcn_s_setprio(0);
    if (kt < 14) STG_A((kt + 2) % 3, kt + 2);   // slot last read kt-1: safe
  }

  // epilogue: C/D layout col = lane&15, row = (lane>>4)*4 + reg
  size_t row0 = (size_t)mt * BM + wm * 64 + (l >> 4) * 4;
  int col0 = nt * BN + wn * 64 + (l & 15);
#pragma unroll
  for (int nf = 0; nf < 4; ++nf) {
    float bv = bias[col0 + nf * 16];
#pragma unroll
    for (int mf = 0; mf < 4; ++mf) {
#pragma unroll
      for (int j = 0; j < 4; ++j)
        out[(row0 + mf * 16 + j) * kDout + col0 + nf * 16] = acc[mf][nf][j] + bv;
    }
  }
}

extern "C" void kernel_launch(void* const* d_in, const int* in_sizes, int n_in,
                              void* d_out, int out_size, void* d_ws, size_t ws_size,
                              hipStream_t stream) {
  const float* h    = (const float*)d_in[0];   // [32,1024,1024] f32
  const int*   aids = (const int*)d_in[1];     // [32] i32
  const float* W    = (const float*)d_in[2];   // [1024,4096] f32
  const float* bias = (const float*)d_in[3];   // [4096] f32
  const float* la   = (const float*)d_in[4];   // [8,1024,16] f32
  const float* lb   = (const float*)d_in[5];   // [8,16,4096] f32
  float* out = (float*)d_out;                  // [32,1024,4096] f32

  unsigned short* Abf  = (unsigned short*)d_ws;
  unsigned short* Weff = Abf + (size_t)kM * kDin;

  prep_kernel<<<kWeffBlocks + kCastBlocks, 256, 0, stream>>>(h, Abf, W, la, lb, Weff);
  gemm256_kernel<<<NWG2, 1024, 0, stream>>>(Abf, Weff, bias, aids, out);
}

// Round 10
// 502.049 us; speedup vs baseline: 1.3039x; 1.3039x over previous
//
#include <hip/hip_runtime.h>
#include <hip/hip_bf16.h>
#include <stdint.h>

// Problem dims (fixed by the reference)
constexpr int kB = 32;
constexpr int kS = 1024;
constexpr int kDin = 1024;
constexpr int kDout = 4096;
constexpr int kRank = 16;
constexpr int kNAdapt = 8;
constexpr int kM = kB * kS;     // 32768 rows
constexpr float kScale = 2.0f;  // alpha/rank = 32/16

typedef __attribute__((ext_vector_type(4))) float f32x4;
typedef __attribute__((ext_vector_type(8))) short s16x8;
typedef __attribute__((ext_vector_type(8))) unsigned short u16x8;
typedef __attribute__((ext_vector_type(4))) unsigned short u16x4;

__device__ __forceinline__ unsigned short f2bf(float f) {
  union { float f; uint32_t u; } x; x.f = f;
  uint32_t u = x.u;
  u += 0x7fffu + ((u >> 16) & 1u);   // round-to-nearest-even
  return (unsigned short)(u >> 16);
}
__device__ __forceinline__ float bf2f(unsigned short b) {
  union { uint32_t u; float f; } x; x.u = (uint32_t)b << 16; return x.f;
}

// ---------- Fused prep kernel, 4 sections ----------
// [0,1024): Wt transpose (W[d][o] f32 -> Wt[o][d] bf16)
// [1024,1152): lbp build (lbp[e][o][r] = bf16(2*lb[e][r][o]), r padded to 32)
// [1152,3200): cast h f32 -> bf16 (grid-stride)
// [3200,3712): lr compute (lr[m][r] = sum_d h[m][d]*la[aid][d][r], padded to 32)
constexpr int kWtBlocks = (kDin / 64) * (kDout / 64);   // 1024
constexpr int kLbpBlocks = kNAdapt * kDout / 256;       // 128
constexpr int kCastBlocks = 2048;
constexpr int kLrBlocks = kM / 64;                      // 512
constexpr int kLbpBase = kWtBlocks;                     // 1024
constexpr int kCastBase = kLbpBase + kLbpBlocks;        // 1152
constexpr int kLrBase = kCastBase + kCastBlocks;        // 3200
constexpr int kPrepBlocks = kLrBase + kLrBlocks;        // 3712

__global__ __launch_bounds__(256) void prep_kernel(
    const float* __restrict__ h, unsigned short* __restrict__ hout,
    const float* __restrict__ W, const float* __restrict__ la,
    const float* __restrict__ lb, const int* __restrict__ aids,
    unsigned short* __restrict__ wt,    // [4096][1024] bf16
    unsigned short* __restrict__ lrp,   // [32768][32] bf16 (k>=16 zero)
    unsigned short* __restrict__ lbp) { // [8][4096][32] bf16 (k>=16 zero)
  __shared__ float Wt[64][68];          // 17.4 KB (Wt section)
  __shared__ unsigned short laS[16384]; // 32 KB (lr section: la bf16 [1024][16])
  __shared__ float redS[4096];          // 16 KB (lr section: [64][4][16])
  int bid = blockIdx.x;
  int t = threadIdx.x;

  if (bid < kWtBlocks) {
    // ---- Wt transpose: 64(d) x 64(o) tile ----
    int dt = bid >> 6, ot = bid & 63;
    int d0 = dt * 64, o0 = ot * 64;
    int r = t >> 4;
    int c = (t & 15) * 4;
    const float* wp = W + (size_t)(d0 + r) * kDout + o0 + c;
#pragma unroll
    for (int p = 0; p < 4; ++p) {
      f32x4 v = *reinterpret_cast<const f32x4*>(wp + (size_t)p * 16 * kDout);
      *reinterpret_cast<f32x4*>(&Wt[p * 16 + r][c]) = v;
    }
    __syncthreads();
    int ol_base = t >> 4;
    int dl = (t & 15) * 4;
#pragma unroll
    for (int p = 0; p < 4; ++p) {
      int ol = p * 16 + ol_base;
      u16x4 r4;
#pragma unroll
      for (int j = 0; j < 4; ++j) r4[j] = f2bf(Wt[dl + j][ol]);
      *reinterpret_cast<u16x4*>(wt + (size_t)(o0 + ol) * kDin + d0 + dl) = r4;
    }
    return;
  }
  if (bid < kCastBase) {
    // ---- lbp: thread per output column o ----
    int oidx = (bid - kLbpBase) * 256 + t;       // 0..32767
    int e = oidx >> 12, o = oidx & (kDout - 1);
    u16x8 lo, hi, z;
#pragma unroll
    for (int r = 0; r < 8; ++r) {
      lo[r] = f2bf(kScale * lb[((size_t)e * kRank + r) * kDout + o]);
      hi[r] = f2bf(kScale * lb[((size_t)e * kRank + 8 + r) * kDout + o]);
      z[r] = 0;
    }
    unsigned short* dst = lbp + (size_t)oidx * 32;
    *reinterpret_cast<u16x8*>(dst) = lo;
    *reinterpret_cast<u16x8*>(dst + 8) = hi;
    *reinterpret_cast<u16x8*>(dst + 16) = z;
    *reinterpret_cast<u16x8*>(dst + 24) = z;
    return;
  }
  if (bid < kLrBase) {
    // ---- cast h -> bf16, grid-stride ----
    int cb = bid - kCastBase;
    size_t base = (size_t)cb * 256 + t;
    constexpr size_t stride = (size_t)kCastBlocks * 256;
    constexpr size_t total8 = (size_t)kM * kDin / 8;
#pragma unroll
    for (int p = 0; p < 8; ++p) {
      size_t i = base + p * stride;
      if (i < total8) {
        const f32x4* src = reinterpret_cast<const f32x4*>(h) + i * 2;
        f32x4 v0 = src[0], v1 = src[1];
        u16x8 rr;
        rr[0] = f2bf(v0[0]); rr[1] = f2bf(v0[1]); rr[2] = f2bf(v0[2]); rr[3] = f2bf(v0[3]);
        rr[4] = f2bf(v1[0]); rr[5] = f2bf(v1[1]); rr[6] = f2bf(v1[2]); rr[7] = f2bf(v1[3]);
        *reinterpret_cast<u16x8*>(hout + i * 8) = rr;
      }
    }
    return;
  }
  // ---- lr: block owns 64 rows (single sample since 64 | 1024) ----
  {
    int j = bid - kLrBase;           // 0..511
    int row0 = j * 64;
    int e = aids[row0 >> 10];
    // stage la[e] -> bf16 LDS, linear [d*16+r]
    const float* lap = la + (size_t)e * kDin * kRank;
#pragma unroll
    for (int c = 0; c < 16; ++c) {
      f32x4 v = *reinterpret_cast<const f32x4*>(lap + c * 1024 + t * 4);
      int o = c * 1024 + t * 4;
      laS[o] = f2bf(v[0]); laS[o + 1] = f2bf(v[1]);
      laS[o + 2] = f2bf(v[2]); laS[o + 3] = f2bf(v[3]);
    }
    __syncthreads();
    int rq = t >> 2;                 // row 0..63
    int q = t & 3;                   // d-quarter
    const float* hp0 = h + (size_t)(row0 + rq) * kDin + q * 256;
    float p[16];
#pragma unroll
    for (int r = 0; r < 16; ++r) p[r] = 0.f;
#pragma unroll
    for (int c = 0; c < 4; ++c) {
      f32x4 hv[16];
#pragma unroll
      for (int i = 0; i < 16; ++i)
        hv[i] = *reinterpret_cast<const f32x4*>(hp0 + c * 64 + i * 4);
#pragma unroll
      for (int dd = 0; dd < 64; ++dd) {
        float v = hv[dd >> 2][dd & 3];
        int d = q * 256 + c * 64 + dd;
        u16x8 l0 = *reinterpret_cast<const u16x8*>(&laS[d * 16]);
        u16x8 l1 = *reinterpret_cast<const u16x8*>(&laS[d * 16 + 8]);
#pragma unroll
        for (int r = 0; r < 8; ++r) {
          p[r] += v * bf2f(l0[r]);
          p[8 + r] += v * bf2f(l1[r]);
        }
      }
    }
#pragma unroll
    for (int r = 0; r < 16; ++r) redS[(rq * 4 + q) * 16 + r] = p[r];
    __syncthreads();
    // reduce 4 quarters; thread t: row t>>2, r-group (t&3)*4
    int row = t >> 2, rg = (t & 3) * 4;
    u16x4 outv, zv;
#pragma unroll
    for (int k = 0; k < 4; ++k) {
      float s = redS[(row * 4 + 0) * 16 + rg + k] + redS[(row * 4 + 1) * 16 + rg + k] +
                redS[(row * 4 + 2) * 16 + rg + k] + redS[(row * 4 + 3) * 16 + rg + k];
      outv[k] = f2bf(s);
      zv[k] = 0;
    }
    unsigned short* dst = lrp + (size_t)(row0 + row) * 32;
    *reinterpret_cast<u16x4*>(dst + rg) = outv;
    *reinterpret_cast<u16x4*>(dst + 16 + rg) = zv;
  }
}

// ---------- GEMM: 256x256 W-direct, single barrier per K-tile, A tribuf +
// B dbuf (R8 core), + 17th "LoRA tile": delta = lrp @ lbp via 32 extra MFMA.
constexpr int BM = 256, BN = 256, BK = 64;
constexpr int MT2 = kM / BM;      // 128
constexpr int NT2 = kDout / BN;   // 16
constexpr int NWG2 = MT2 * NT2;   // 2048

__device__ __forceinline__ void gload16(const unsigned short* g, unsigned short* l) {
  __builtin_amdgcn_global_load_lds((const __attribute__((address_space(1))) void*)g,
                                   (__attribute__((address_space(3))) void*)l, 16, 0, 0);
}

#define STG_A(s, kk) do { \
  gload16(gA + (kk) * 64, ldst + (s) * 16384); \
  gload16(gA + (size_t)64 * kDin + (kk) * 64, ldst + (s) * 16384 + 4096); \
  gload16(gA + (size_t)128 * kDin + (kk) * 64, ldst + (s) * 16384 + 8192); \
  gload16(gA + (size_t)192 * kDin + (kk) * 64, ldst + (s) * 16384 + 12288); \
} while (0)
#define STG_B(s, kk) do { \
  gload16(gB + (kk) * 64, ldst + 49152 + (s) * 16384); \
  gload16(gB + (size_t)64 * kDin + (kk) * 64, ldst + 49152 + (s) * 16384 + 4096); \
  gload16(gB + (size_t)128 * kDin + (kk) * 64, ldst + 49152 + (s) * 16384 + 8192); \
  gload16(gB + (size_t)192 * kDin + (kk) * 64, ldst + 49152 + (s) * 16384 + 12288); \
} while (0)

#define RD_A(mh, s) do { _Pragma("unroll") for (int ii = 0; ii < 4; ++ii) { \
  a[ii][0] = *(const s16x8*)&lds[(s) * 16384 + aRow + ((mh) * 4 + ii) * 1024 + e0]; \
  a[ii][1] = *(const s16x8*)&lds[(s) * 16384 + aRow + ((mh) * 4 + ii) * 1024 + e1]; } } while (0)
#define RD_B(nh, breg, s) do { _Pragma("unroll") for (int jj = 0; jj < 2; ++jj) { \
  breg[jj][0] = *(const s16x8*)&lds[49152 + (s) * 16384 + bRow + ((nh) * 2 + jj) * 1024 + e0]; \
  breg[jj][1] = *(const s16x8*)&lds[49152 + (s) * 16384 + bRow + ((nh) * 2 + jj) * 1024 + e1]; } } while (0)

#define MMQ(mh, nh, breg) do { \
  _Pragma("unroll") for (int ii = 0; ii < 4; ++ii) \
  _Pragma("unroll") for (int jj = 0; jj < 2; ++jj) { \
    acc[(mh) * 4 + ii][(nh) * 2 + jj] = __builtin_amdgcn_mfma_f32_16x16x32_bf16( \
        a[ii][0], breg[jj][0], acc[(mh) * 4 + ii][(nh) * 2 + jj], 0, 0, 0); \
    acc[(mh) * 4 + ii][(nh) * 2 + jj] = __builtin_amdgcn_mfma_f32_16x16x32_bf16( \
        a[ii][1], breg[jj][1], acc[(mh) * 4 + ii][(nh) * 2 + jj], 0, 0, 0); } \
} while (0)

#define VMC(n) asm volatile("s_waitcnt vmcnt(" #n ")" ::: "memory")

__global__ __launch_bounds__(512, 2) void gemm256_kernel(
    const unsigned short* __restrict__ Ab,    // [M][K] bf16
    const unsigned short* __restrict__ Wt,    // [N][K] bf16
    const unsigned short* __restrict__ lrp,   // [M][32] bf16
    const unsigned short* __restrict__ lbp,   // [NA][N][32] bf16
    const float* __restrict__ bias,
    const int* __restrict__ aids,
    float* __restrict__ out) {
  __shared__ unsigned short lds[81920];   // 160 KiB: A[3] + B[2] slots
  int bid = blockIdx.x;
  int swz = (bid & 7) * (NWG2 / 8) + (bid >> 3);   // XCD-aware, bijective
  int mt = swz >> 4, nt = swz & 15;
  int aid = aids[mt >> 2];
  const unsigned short* Aptr = Ab + (size_t)mt * BM * kDin;
  const unsigned short* Bptr = Wt + (size_t)nt * BN * kDin;

  int t = threadIdx.x;
  int l = t & 63;
  int w = t >> 6;
  int wm = w >> 2;   // 0..1 (M)
  int wn = w & 3;    // 0..3 (N)

  int srcColEl = ((t & 7) * 8) ^ (((t >> 3) & 7) << 3);
  const unsigned short* gA = Aptr + (size_t)(t >> 3) * kDin + srcColEl;
  const unsigned short* gB = Bptr + (size_t)(t >> 3) * kDin + srcColEl;
  unsigned short* ldst = lds + t * 8;

  int xmEl = (l & 7) << 3;
  int e0 = (((l >> 4) * 8) ^ xmEl);
  int e1 = e0 ^ 32;
  int aRow = (wm * 128 + (l & 15)) * 64;
  int bRow = (wn * 64 + (l & 15)) * 64;

  f32x4 acc[8][4];
#pragma unroll
  for (int m = 0; m < 8; ++m)
#pragma unroll
    for (int n = 0; n < 4; ++n) acc[m][n] = f32x4{0.f, 0.f, 0.f, 0.f};
  s16x8 a[4][2], b0[2][2], b1[2][2];

  // prologue FIFO: [A0(4), B0(4), A1(4)]
  STG_A(0, 0); STG_B(0, 0); STG_A(1, 1);

#pragma unroll
  for (int kt = 0; kt < 16; ++kt) {
    const int sa = kt % 3;
    const int sb = kt & 1;
    if (kt < 15) { VMC(4); } else { VMC(0); }
    __builtin_amdgcn_s_barrier();
    __builtin_amdgcn_sched_barrier(0);
    if (kt < 15) STG_B((kt + 1) & 1, kt + 1);
    RD_A(0, sa);
    RD_B(0, b0, sb); RD_B(1, b1, sb);
    MMQ(0, 0, b0); MMQ(0, 1, b1);
    RD_A(1, sa);
    MMQ(1, 0, b0); MMQ(1, 1, b1);
    if (kt < 14) STG_A((kt + 2) % 3, kt + 2);
  }

  // ---- 17th tile: LoRA delta = lrp(tile) @ lbp(tile), K=32 (16 real) ----
  __builtin_amdgcn_s_barrier();                   // all reads of slots done
  {
    const unsigned short* glr = lrp + (size_t)mt * BM * 32;
    const unsigned short* glb = lbp + ((size_t)aid * kDout + (size_t)nt * BN) * 32;
    // linear copies: 8192 el each, 512 thr x 8 el x 2 rounds
    gload16(glr + t * 8, lds + t * 8);
    gload16(glr + 4096 + t * 8, lds + 4096 + t * 8);
    gload16(glb + t * 8, lds + 8192 + t * 8);
    gload16(glb + 4096 + t * 8, lds + 12288 + t * 8);
  }
  VMC(0);
  __builtin_amdgcn_s_barrier();
  {
    int kq = (l >> 4) * 8;   // k-offset 0/8/16/24 (16..31 are zero pad)
#pragma unroll
    for (int mf = 0; mf < 8; ++mf)
      a[mf >> 1][mf & 1] = *(const s16x8*)&lds[(wm * 128 + mf * 16 + (l & 15)) * 32 + kq];
#pragma unroll
    for (int nf = 0; nf < 4; ++nf)
      b0[nf >> 1][nf & 1] = *(const s16x8*)&lds[8192 + (wn * 64 + nf * 16 + (l & 15)) * 32 + kq];
#pragma unroll
    for (int mf = 0; mf < 8; ++mf)
#pragma unroll
      for (int nf = 0; nf < 4; ++nf)
        acc[mf][nf] = __builtin_amdgcn_mfma_f32_16x16x32_bf16(
            a[mf >> 1][mf & 1], b0[nf >> 1][nf & 1], acc[mf][nf], 0, 0, 0);
  }

  // epilogue: C/D layout col = lane&15, row = (lane>>4)*4 + reg
  size_t row0 = (size_t)mt * BM + wm * 128 + (l >> 4) * 4;
  int col0 = nt * BN + wn * 64 + (l & 15);
#pragma unroll
  for (int nf = 0; nf < 4; ++nf) {
    float bv = bias[col0 + nf * 16];
#pragma unroll
    for (int mf = 0; mf < 8; ++mf) {
#pragma unroll
      for (int j = 0; j < 4; ++j)
        out[(row0 + mf * 16 + j) * kDout + col0 + nf * 16] = acc[mf][nf][j] + bv;
    }
  }
}

extern "C" void kernel_launch(void* const* d_in, const int* in_sizes, int n_in,
                              void* d_out, int out_size, void* d_ws, size_t ws_size,
                              hipStream_t stream) {
  const float* h    = (const float*)d_in[0];   // [32,1024,1024] f32
  const int*   aids = (const int*)d_in[1];     // [32] i32
  const float* W    = (const float*)d_in[2];   // [1024,4096] f32
  const float* bias = (const float*)d_in[3];   // [4096] f32
  const float* la   = (const float*)d_in[4];   // [8,1024,16] f32
  const float* lb   = (const float*)d_in[5];   // [8,16,4096] f32
  float* out = (float*)d_out;                  // [32,1024,4096] f32

  unsigned short* Abf = (unsigned short*)d_ws;                       // 64 MB
  unsigned short* WtB = Abf + (size_t)kM * kDin;                     // 8 MB
  unsigned short* lrp = WtB + (size_t)kDout * kDin;                  // 2 MB
  unsigned short* lbp = lrp + (size_t)kM * 32;                       // 2 MB

  prep_kernel<<<kPrepBlocks, 256, 0, stream>>>(h, Abf, W, la, lb, aids, WtB, lrp, lbp);
  gemm256_kernel<<<NWG2, 512, 0, stream>>>(Abf, WtB, lrp, lbp, bias, aids, out);
}

// Round 11
// 386.829 us; speedup vs baseline: 1.6922x; 1.2979x over previous
//
#include <hip/hip_runtime.h>
#include <hip/hip_bf16.h>
#include <stdint.h>

// Problem dims (fixed by the reference)
constexpr int kB = 32;
constexpr int kS = 1024;
constexpr int kDin = 1024;
constexpr int kDout = 4096;
constexpr int kRank = 16;
constexpr int kNAdapt = 8;
constexpr int kM = kB * kS;     // 32768 rows
constexpr float kScale = 2.0f;  // alpha/rank = 32/16

typedef __attribute__((ext_vector_type(4))) float f32x4;
typedef __attribute__((ext_vector_type(8))) short s16x8;
typedef __attribute__((ext_vector_type(8))) unsigned short u16x8;
typedef __attribute__((ext_vector_type(4))) unsigned short u16x4;

__device__ __forceinline__ unsigned short f2bf(float f) {
  union { float f; uint32_t u; } x; x.f = f;
  uint32_t u = x.u;
  u += 0x7fffu + ((u >> 16) & 1u);   // round-to-nearest-even
  return (unsigned short)(u >> 16);
}

// ---------- Fused prep kernel: weff blocks (bid<8192) + cast grid-stride ----------
// (R8 version, measured ~50us total)
constexpr int kWeffBlocks = kNAdapt * (kDin / 64) * (kDout / 64);   // 8192
constexpr int kCastBlocks = 2048;

__global__ __launch_bounds__(256) void prep_kernel(
    const float* __restrict__ h, unsigned short* __restrict__ hout,
    const float* __restrict__ W, const float* __restrict__ la,
    const float* __restrict__ lb, unsigned short* __restrict__ weff) {
  __shared__ float Wt[64][68];
  __shared__ float At[64][20];
  __shared__ float Bt[16][68];
  int bid = blockIdx.x;
  int t = threadIdx.x;
  if (bid >= kWeffBlocks) {
    int cb = bid - kWeffBlocks;
    size_t base = (size_t)cb * 256 + t;
    constexpr size_t stride = (size_t)kCastBlocks * 256;
    constexpr size_t total8 = (size_t)kM * kDin / 8;
#pragma unroll
    for (int p = 0; p < 8; ++p) {
      size_t i = base + p * stride;
      if (i < total8) {
        const f32x4* src = reinterpret_cast<const f32x4*>(h) + i * 2;
        f32x4 v0 = src[0], v1 = src[1];
        u16x8 r;
        r[0] = f2bf(v0[0]); r[1] = f2bf(v0[1]); r[2] = f2bf(v0[2]); r[3] = f2bf(v0[3]);
        r[4] = f2bf(v1[0]); r[5] = f2bf(v1[1]); r[6] = f2bf(v1[2]); r[7] = f2bf(v1[3]);
        *reinterpret_cast<u16x8*>(hout + i * 8) = r;
      }
    }
    return;
  }
  int e = bid & 7;
  int rem = bid >> 3;
  int dt = rem >> 6;
  int ot = rem & 63;
  int d0 = dt * 64, o0 = ot * 64;
  {
    int r = t >> 4;
    int c = (t & 15) * 4;
    const float* wp = W + (size_t)(d0 + r) * kDout + o0 + c;
#pragma unroll
    for (int p = 0; p < 4; ++p) {
      f32x4 v = *reinterpret_cast<const f32x4*>(wp + (size_t)p * 16 * kDout);
      *reinterpret_cast<f32x4*>(&Wt[p * 16 + r][c]) = v;
    }
  }
  {
    int d = t >> 2, r4 = (t & 3) * 4;
    f32x4 v = *reinterpret_cast<const f32x4*>(la + ((size_t)e * kDin + d0 + d) * kRank + r4);
    *reinterpret_cast<f32x4*>(&At[d][r4]) = v;
  }
  {
    int r = t >> 4, c = (t & 15) * 4;
    f32x4 v = *reinterpret_cast<const f32x4*>(lb + ((size_t)e * kRank + r) * kDout + o0 + c);
    *reinterpret_cast<f32x4*>(&Bt[r][c]) = v;
  }
  __syncthreads();
  int ol_base = t >> 4;
  int dl = (t & 15) * 4;
  f32x4 areg[4][4];
#pragma unroll
  for (int j = 0; j < 4; ++j)
#pragma unroll
    for (int q = 0; q < 4; ++q)
      areg[j][q] = *reinterpret_cast<const f32x4*>(&At[dl + j][q * 4]);
#pragma unroll
  for (int p = 0; p < 4; ++p) {
    int ol = p * 16 + ol_base;
    float bv[kRank];
#pragma unroll
    for (int r = 0; r < kRank; ++r) bv[r] = Bt[r][ol];
    u16x4 r4;
#pragma unroll
    for (int j = 0; j < 4; ++j) {
      float acc = 0.f;
#pragma unroll
      for (int q = 0; q < 4; ++q)
        acc += areg[j][q][0] * bv[q * 4 + 0] + areg[j][q][1] * bv[q * 4 + 1] +
               areg[j][q][2] * bv[q * 4 + 2] + areg[j][q][3] * bv[q * 4 + 3];
      r4[j] = f2bf(Wt[dl + j][ol] + kScale * acc);
    }
    *reinterpret_cast<u16x4*>(weff + ((size_t)e * kDout + o0 + ol) * kDin + d0 + dl) = r4;
  }
}

// ---------- GEMM: R8 core (single barrier/K-tile, A tribuf + B dbuf) +
// LDS-transposed epilogue with full-line float4 stores.
constexpr int BM = 256, BN = 256, BK = 64;
constexpr int MT2 = kM / BM;      // 128
constexpr int NT2 = kDout / BN;   // 16
constexpr int NWG2 = MT2 * NT2;   // 2048

__device__ __forceinline__ void gload16(const unsigned short* g, unsigned short* l) {
  __builtin_amdgcn_global_load_lds((const __attribute__((address_space(1))) void*)g,
                                   (__attribute__((address_space(3))) void*)l, 16, 0, 0);
}

// LDS elem layout: A slot s in [0,3): s*16384 + instr*4096 + t*8
//                  B slot s in [0,2): 49152 + s*16384 + instr*4096 + t*8
// logical (row r, elem c) lives at r*64 + (c ^ ((r&7)<<3)); source pre-swizzled.
#define STG_A(s, kk) do { \
  gload16(gA + (kk) * 64, ldst + (s) * 16384); \
  gload16(gA + (size_t)64 * kDin + (kk) * 64, ldst + (s) * 16384 + 4096); \
  gload16(gA + (size_t)128 * kDin + (kk) * 64, ldst + (s) * 16384 + 8192); \
  gload16(gA + (size_t)192 * kDin + (kk) * 64, ldst + (s) * 16384 + 12288); \
} while (0)
#define STG_B(s, kk) do { \
  gload16(gB + (kk) * 64, ldst + 49152 + (s) * 16384); \
  gload16(gB + (size_t)64 * kDin + (kk) * 64, ldst + 49152 + (s) * 16384 + 4096); \
  gload16(gB + (size_t)128 * kDin + (kk) * 64, ldst + 49152 + (s) * 16384 + 8192); \
  gload16(gB + (size_t)192 * kDin + (kk) * 64, ldst + 49152 + (s) * 16384 + 12288); \
} while (0)

#define RD_A(mh, s) do { _Pragma("unroll") for (int ii = 0; ii < 4; ++ii) { \
  a[ii][0] = *(const s16x8*)&lds[(s) * 16384 + aRow + ((mh) * 4 + ii) * 1024 + e0]; \
  a[ii][1] = *(const s16x8*)&lds[(s) * 16384 + aRow + ((mh) * 4 + ii) * 1024 + e1]; } } while (0)
#define RD_B(nh, breg, s) do { _Pragma("unroll") for (int jj = 0; jj < 2; ++jj) { \
  breg[jj][0] = *(const s16x8*)&lds[49152 + (s) * 16384 + bRow + ((nh) * 2 + jj) * 1024 + e0]; \
  breg[jj][1] = *(const s16x8*)&lds[49152 + (s) * 16384 + bRow + ((nh) * 2 + jj) * 1024 + e1]; } } while (0)

#define MMQ(mh, nh, breg) do { \
  _Pragma("unroll") for (int ii = 0; ii < 4; ++ii) \
  _Pragma("unroll") for (int jj = 0; jj < 2; ++jj) { \
    acc[(mh) * 4 + ii][(nh) * 2 + jj] = __builtin_amdgcn_mfma_f32_16x16x32_bf16( \
        a[ii][0], breg[jj][0], acc[(mh) * 4 + ii][(nh) * 2 + jj], 0, 0, 0); \
    acc[(mh) * 4 + ii][(nh) * 2 + jj] = __builtin_amdgcn_mfma_f32_16x16x32_bf16( \
        a[ii][1], breg[jj][1], acc[(mh) * 4 + ii][(nh) * 2 + jj], 0, 0, 0); } \
} while (0)

#define VMC(n) asm volatile("s_waitcnt vmcnt(" #n ")" ::: "memory")

__global__ __launch_bounds__(512, 2) void gemm256_kernel(
    const unsigned short* __restrict__ Ab,    // [M][K] bf16
    const unsigned short* __restrict__ Weff,  // [NA][N][K] bf16
    const float* __restrict__ bias,
    const int* __restrict__ aids,
    float* __restrict__ out) {
  __shared__ unsigned short lds[81920];   // 160 KiB: A[3] + B[2] slots
  int bid = blockIdx.x;
  int swz = (bid & 7) * (NWG2 / 8) + (bid >> 3);   // XCD-aware, bijective
  int mt = swz >> 4, nt = swz & 15;
  int aid = aids[mt >> 2];   // BM=256 divides S=1024: one sample per M-tile
  const unsigned short* Aptr = Ab + (size_t)mt * BM * kDin;
  const unsigned short* Bptr = Weff + ((size_t)aid * kDout + (size_t)nt * BN) * kDin;

  int t = threadIdx.x;
  int l = t & 63;
  int w = t >> 6;
  int wm = w >> 2;   // 0..1 (M)
  int wn = w & 3;    // 0..3 (N)

  int srcColEl = ((t & 7) * 8) ^ (((t >> 3) & 7) << 3);
  const unsigned short* gA = Aptr + (size_t)(t >> 3) * kDin + srcColEl;
  const unsigned short* gB = Bptr + (size_t)(t >> 3) * kDin + srcColEl;
  unsigned short* ldst = lds + t * 8;

  int xmEl = (l & 7) << 3;
  int e0 = (((l >> 4) * 8) ^ xmEl);
  int e1 = e0 ^ 32;
  int aRow = (wm * 128 + (l & 15)) * 64;
  int bRow = (wn * 64 + (l & 15)) * 64;

  f32x4 acc[8][4];
#pragma unroll
  for (int m = 0; m < 8; ++m)
#pragma unroll
    for (int n = 0; n < 4; ++n) acc[m][n] = f32x4{0.f, 0.f, 0.f, 0.f};
  s16x8 a[4][2], b0[2][2], b1[2][2];

  // prologue FIFO: [A0(4), B0(4), A1(4)]
  STG_A(0, 0); STG_B(0, 0); STG_A(1, 1);

#pragma unroll
  for (int kt = 0; kt < 16; ++kt) {
    const int sa = kt % 3;
    const int sb = kt & 1;
    if (kt < 15) { VMC(4); } else { VMC(0); }
    __builtin_amdgcn_s_barrier();
    __builtin_amdgcn_sched_barrier(0);
    if (kt < 15) STG_B((kt + 1) & 1, kt + 1);
    RD_A(0, sa);
    RD_B(0, b0, sb); RD_B(1, b1, sb);
    MMQ(0, 0, b0); MMQ(0, 1, b1);
    RD_A(1, sa);
    MMQ(1, 0, b0); MMQ(1, 1, b1);
    if (kt < 14) STG_A((kt + 2) % 3, kt + 2);
  }

  // ---- epilogue: LDS-transpose, full-128B-line float4 stores ----
  // Per wave: private region of 128 rows x 36 f32 (18 KB); 2 passes of 32 cols.
  // Write side: (36r+c)%32 -> exactly 2 lanes/bank (free, m136). Read side:
  // uniform 8 accesses/bank (minimum). Each store: 8 lanes x 16B = 128B line.
  asm volatile("s_waitcnt lgkmcnt(0)" ::: "memory");
  __builtin_amdgcn_s_barrier();           // all waves done reading K-loop LDS
  {
    float* fl = reinterpret_cast<float*>(lds);
    const int wbase = w * (128 * 36);     // 18432 B per wave, 147456 B total
    int c_lane = l & 15;
    int g4 = (l >> 4) * 4;
    int c4 = (l & 7) * 4;
    int r8 = l >> 3;
#pragma unroll
    for (int p = 0; p < 2; ++p) {
      // stage pass p (cols p*32 .. p*32+31 of the wave's 64-col strip)
#pragma unroll
      for (int q = 0; q < 2; ++q) {
        int nf = p * 2 + q;
#pragma unroll
        for (int mf = 0; mf < 8; ++mf) {
#pragma unroll
          for (int j = 0; j < 4; ++j)
            fl[wbase + (mf * 16 + g4 + j) * 36 + q * 16 + c_lane] = acc[mf][nf][j];
        }
      }
      // read back + bias + full-line store (same-wave LDS ordering via lgkmcnt)
      int colbase = nt * BN + wn * 64 + p * 32;
      f32x4 bv4 = *reinterpret_cast<const f32x4*>(&bias[colbase + c4]);
      size_t rowabs0 = (size_t)mt * BM + wm * 128 + r8;
#pragma unroll
      for (int it = 0; it < 16; ++it) {
        f32x4 v = *reinterpret_cast<const f32x4*>(&fl[wbase + (it * 8 + r8) * 36 + c4]);
        v += bv4;
        *reinterpret_cast<f32x4*>(&out[(rowabs0 + it * 8) * kDout + colbase + c4]) = v;
      }
    }
  }
}

extern "C" void kernel_launch(void* const* d_in, const int* in_sizes, int n_in,
                              void* d_out, int out_size, void* d_ws, size_t ws_size,
                              hipStream_t stream) {
  const float* h    = (const float*)d_in[0];   // [32,1024,1024] f32
  const int*   aids = (const int*)d_in[1];     // [32] i32
  const float* W    = (const float*)d_in[2];   // [1024,4096] f32
  const float* bias = (const float*)d_in[3];   // [4096] f32
  const float* la   = (const float*)d_in[4];   // [8,1024,16] f32
  const float* lb   = (const float*)d_in[5];   // [8,16,4096] f32
  float* out = (float*)d_out;                  // [32,1024,4096] f32

  unsigned short* Abf  = (unsigned short*)d_ws;
  unsigned short* Weff = Abf + (size_t)kM * kDin;

  prep_kernel<<<kWeffBlocks + kCastBlocks, 256, 0, stream>>>(h, Abf, W, la, lb, Weff);
  gemm256_kernel<<<NWG2, 512, 0, stream>>>(Abf, Weff, bias, aids, out);
}

// Round 12
// 378.304 us; speedup vs baseline: 1.7304x; 1.0225x over previous
//
#include <hip/hip_runtime.h>
#include <hip/hip_bf16.h>
#include <stdint.h>

// Problem dims (fixed by the reference)
constexpr int kB = 32;
constexpr int kS = 1024;
constexpr int kDin = 1024;
constexpr int kDout = 4096;
constexpr int kRank = 16;
constexpr int kNAdapt = 8;
constexpr int kM = kB * kS;     // 32768 rows
constexpr float kScale = 2.0f;  // alpha/rank = 32/16

typedef __attribute__((ext_vector_type(4))) float f32x4;
typedef __attribute__((ext_vector_type(8))) short s16x8;
typedef __attribute__((ext_vector_type(8))) unsigned short u16x8;
typedef __attribute__((ext_vector_type(4))) unsigned short u16x4;

__device__ __forceinline__ unsigned short f2bf(float f) {
  union { float f; uint32_t u; } x; x.f = f;
  uint32_t u = x.u;
  u += 0x7fffu + ((u >> 16) & 1u);   // round-to-nearest-even
  return (unsigned short)(u >> 16);
}

// ---------- Fused prep kernel ----------
// bid < 2048: cast h f32->bf16 (grid-stride, BW-bound, starts streaming first)
// bid >= 2048: weff, 4 o-tiles per block (2048 blocks; At loaded once)
constexpr int kCastBlocks = 2048;
constexpr int kWeffBlocks = kNAdapt * (kDin / 64) * (kDout / 256);   // 2048
constexpr int kPrepBlocks = kCastBlocks + kWeffBlocks;               // 4096

__global__ __launch_bounds__(256) void prep_kernel(
    const float* __restrict__ h, unsigned short* __restrict__ hout,
    const float* __restrict__ W, const float* __restrict__ la,
    const float* __restrict__ lb, unsigned short* __restrict__ weff) {
  __shared__ float Wt[64][68];
  __shared__ float At[64][20];
  __shared__ float Bt[16][68];
  int bid = blockIdx.x;
  int t = threadIdx.x;
  if (bid < kCastBlocks) {
    size_t base = (size_t)bid * 256 + t;
    constexpr size_t stride = (size_t)kCastBlocks * 256;
    constexpr size_t total8 = (size_t)kM * kDin / 8;
#pragma unroll
    for (int p = 0; p < 8; ++p) {
      size_t i = base + p * stride;
      if (i < total8) {
        const f32x4* src = reinterpret_cast<const f32x4*>(h) + i * 2;
        f32x4 v0 = src[0], v1 = src[1];
        u16x8 r;
        r[0] = f2bf(v0[0]); r[1] = f2bf(v0[1]); r[2] = f2bf(v0[2]); r[3] = f2bf(v0[3]);
        r[4] = f2bf(v1[0]); r[5] = f2bf(v1[1]); r[6] = f2bf(v1[2]); r[7] = f2bf(v1[3]);
        *reinterpret_cast<u16x8*>(hout + i * 8) = r;
      }
    }
    return;
  }
  // ---- weff: 4 o-tiles per block, same (e, d-tile) ----
  int idx = bid - kCastBlocks;
  int e = idx & 7;
  int rem = idx >> 3;            // 0..255
  int dt = rem >> 4;             // 0..15
  int og = rem & 15;             // 0..15 (o-group of 256 cols)
  int d0 = dt * 64;
  {
    int d = t >> 2, r4 = (t & 3) * 4;
    f32x4 v = *reinterpret_cast<const f32x4*>(la + ((size_t)e * kDin + d0 + d) * kRank + r4);
    *reinterpret_cast<f32x4*>(&At[d][r4]) = v;
  }
  int dl = (t & 15) * 4;
  int ol_base = t >> 4;
  f32x4 areg[4][4];
#pragma unroll 1
  for (int p4 = 0; p4 < 4; ++p4) {
    int o0 = og * 256 + p4 * 64;
    {
      int r = t >> 4;
      int c = (t & 15) * 4;
      const float* wp = W + (size_t)(d0 + r) * kDout + o0 + c;
#pragma unroll
      for (int p = 0; p < 4; ++p) {
        f32x4 v = *reinterpret_cast<const f32x4*>(wp + (size_t)p * 16 * kDout);
        *reinterpret_cast<f32x4*>(&Wt[p * 16 + r][c]) = v;
      }
    }
    {
      int r = t >> 4, c = (t & 15) * 4;
      f32x4 v = *reinterpret_cast<const f32x4*>(lb + ((size_t)e * kRank + r) * kDout + o0 + c);
      *reinterpret_cast<f32x4*>(&Bt[r][c]) = v;
    }
    __syncthreads();
    if (p4 == 0) {
#pragma unroll
      for (int j = 0; j < 4; ++j)
#pragma unroll
        for (int q = 0; q < 4; ++q)
          areg[j][q] = *reinterpret_cast<const f32x4*>(&At[dl + j][q * 4]);
    }
#pragma unroll
    for (int p = 0; p < 4; ++p) {
      int ol = p * 16 + ol_base;
      float bv[kRank];
#pragma unroll
      for (int r = 0; r < kRank; ++r) bv[r] = Bt[r][ol];
      u16x4 r4;
#pragma unroll
      for (int j = 0; j < 4; ++j) {
        float acc = 0.f;
#pragma unroll
        for (int q = 0; q < 4; ++q)
          acc += areg[j][q][0] * bv[q * 4 + 0] + areg[j][q][1] * bv[q * 4 + 1] +
                 areg[j][q][2] * bv[q * 4 + 2] + areg[j][q][3] * bv[q * 4 + 3];
        r4[j] = f2bf(Wt[dl + j][ol] + kScale * acc);
      }
      *reinterpret_cast<u16x4*>(weff + ((size_t)e * kDout + o0 + ol) * kDin + d0 + dl) = r4;
    }
    if (p4 < 3) __syncthreads();   // WAR: Wt/Bt reused next pass
  }
}

// ---------- GEMM: R8 core (single barrier/K-tile, A tribuf + B dbuf) +
// LDS-transposed epilogue (R11) + setprio around MFMA clusters (dynamic
// wave stagger on the fence-free body).
constexpr int BM = 256, BN = 256, BK = 64;
constexpr int MT2 = kM / BM;      // 128
constexpr int NT2 = kDout / BN;   // 16
constexpr int NWG2 = MT2 * NT2;   // 2048

__device__ __forceinline__ void gload16(const unsigned short* g, unsigned short* l) {
  __builtin_amdgcn_global_load_lds((const __attribute__((address_space(1))) void*)g,
                                   (__attribute__((address_space(3))) void*)l, 16, 0, 0);
}

// LDS elem layout: A slot s in [0,3): s*16384 + instr*4096 + t*8
//                  B slot s in [0,2): 49152 + s*16384 + instr*4096 + t*8
// logical (row r, elem c) lives at r*64 + (c ^ ((r&7)<<3)); source pre-swizzled.
#define STG_A(s, kk) do { \
  gload16(gA + (kk) * 64, ldst + (s) * 16384); \
  gload16(gA + (size_t)64 * kDin + (kk) * 64, ldst + (s) * 16384 + 4096); \
  gload16(gA + (size_t)128 * kDin + (kk) * 64, ldst + (s) * 16384 + 8192); \
  gload16(gA + (size_t)192 * kDin + (kk) * 64, ldst + (s) * 16384 + 12288); \
} while (0)
#define STG_B(s, kk) do { \
  gload16(gB + (kk) * 64, ldst + 49152 + (s) * 16384); \
  gload16(gB + (size_t)64 * kDin + (kk) * 64, ldst + 49152 + (s) * 16384 + 4096); \
  gload16(gB + (size_t)128 * kDin + (kk) * 64, ldst + 49152 + (s) * 16384 + 8192); \
  gload16(gB + (size_t)192 * kDin + (kk) * 64, ldst + 49152 + (s) * 16384 + 12288); \
} while (0)

#define RD_A(mh, s) do { _Pragma("unroll") for (int ii = 0; ii < 4; ++ii) { \
  a[ii][0] = *(const s16x8*)&lds[(s) * 16384 + aRow + ((mh) * 4 + ii) * 1024 + e0]; \
  a[ii][1] = *(const s16x8*)&lds[(s) * 16384 + aRow + ((mh) * 4 + ii) * 1024 + e1]; } } while (0)
#define RD_B(nh, breg, s) do { _Pragma("unroll") for (int jj = 0; jj < 2; ++jj) { \
  breg[jj][0] = *(const s16x8*)&lds[49152 + (s) * 16384 + bRow + ((nh) * 2 + jj) * 1024 + e0]; \
  breg[jj][1] = *(const s16x8*)&lds[49152 + (s) * 16384 + bRow + ((nh) * 2 + jj) * 1024 + e1]; } } while (0)

#define MMQ(mh, nh, breg) do { \
  _Pragma("unroll") for (int ii = 0; ii < 4; ++ii) \
  _Pragma("unroll") for (int jj = 0; jj < 2; ++jj) { \
    acc[(mh) * 4 + ii][(nh) * 2 + jj] = __builtin_amdgcn_mfma_f32_16x16x32_bf16( \
        a[ii][0], breg[jj][0], acc[(mh) * 4 + ii][(nh) * 2 + jj], 0, 0, 0); \
    acc[(mh) * 4 + ii][(nh) * 2 + jj] = __builtin_amdgcn_mfma_f32_16x16x32_bf16( \
        a[ii][1], breg[jj][1], acc[(mh) * 4 + ii][(nh) * 2 + jj], 0, 0, 0); } \
} while (0)

#define VMC(n) asm volatile("s_waitcnt vmcnt(" #n ")" ::: "memory")

__global__ __launch_bounds__(512, 2) void gemm256_kernel(
    const unsigned short* __restrict__ Ab,    // [M][K] bf16
    const unsigned short* __restrict__ Weff,  // [NA][N][K] bf16
    const float* __restrict__ bias,
    const int* __restrict__ aids,
    float* __restrict__ out) {
  __shared__ unsigned short lds[81920];   // 160 KiB: A[3] + B[2] slots
  int bid = blockIdx.x;
  int swz = (bid & 7) * (NWG2 / 8) + (bid >> 3);   // XCD-aware, bijective
  int mt = swz >> 4, nt = swz & 15;
  int aid = aids[mt >> 2];   // BM=256 divides S=1024: one sample per M-tile
  const unsigned short* Aptr = Ab + (size_t)mt * BM * kDin;
  const unsigned short* Bptr = Weff + ((size_t)aid * kDout + (size_t)nt * BN) * kDin;

  int t = threadIdx.x;
  int l = t & 63;
  int w = t >> 6;
  int wm = w >> 2;   // 0..1 (M)
  int wn = w & 3;    // 0..3 (N)

  int srcColEl = ((t & 7) * 8) ^ (((t >> 3) & 7) << 3);
  const unsigned short* gA = Aptr + (size_t)(t >> 3) * kDin + srcColEl;
  const unsigned short* gB = Bptr + (size_t)(t >> 3) * kDin + srcColEl;
  unsigned short* ldst = lds + t * 8;

  int xmEl = (l & 7) << 3;
  int e0 = (((l >> 4) * 8) ^ xmEl);
  int e1 = e0 ^ 32;
  int aRow = (wm * 128 + (l & 15)) * 64;
  int bRow = (wn * 64 + (l & 15)) * 64;

  f32x4 acc[8][4];
#pragma unroll
  for (int m = 0; m < 8; ++m)
#pragma unroll
    for (int n = 0; n < 4; ++n) acc[m][n] = f32x4{0.f, 0.f, 0.f, 0.f};
  s16x8 a[4][2], b0[2][2], b1[2][2];

  // prologue FIFO: [A0(4), B0(4), A1(4)]
  STG_A(0, 0); STG_B(0, 0); STG_A(1, 1);

#pragma unroll
  for (int kt = 0; kt < 16; ++kt) {
    const int sa = kt % 3;
    const int sb = kt & 1;
    if (kt < 15) { VMC(4); } else { VMC(0); }
    __builtin_amdgcn_s_barrier();
    __builtin_amdgcn_sched_barrier(0);
    if (kt < 15) STG_B((kt + 1) & 1, kt + 1);
    RD_A(0, sa);
    RD_B(0, b0, sb); RD_B(1, b1, sb);
    __builtin_amdgcn_s_setprio(1);
    MMQ(0, 0, b0); MMQ(0, 1, b1);
    __builtin_amdgcn_s_setprio(0);
    RD_A(1, sa);
    __builtin_amdgcn_s_setprio(1);
    MMQ(1, 0, b0); MMQ(1, 1, b1);
    __builtin_amdgcn_s_setprio(0);
    if (kt < 14) STG_A((kt + 2) % 3, kt + 2);
  }

  // ---- epilogue: LDS-transpose, full-128B-line float4 stores (R11) ----
  asm volatile("s_waitcnt lgkmcnt(0)" ::: "memory");
  __builtin_amdgcn_s_barrier();           // all waves done reading K-loop LDS
  {
    float* fl = reinterpret_cast<float*>(lds);
    const int wbase = w * (128 * 36);     // 18432 B per wave
    int c_lane = l & 15;
    int g4 = (l >> 4) * 4;
    int c4 = (l & 7) * 4;
    int r8 = l >> 3;
#pragma unroll
    for (int p = 0; p < 2; ++p) {
#pragma unroll
      for (int q = 0; q < 2; ++q) {
        int nf = p * 2 + q;
#pragma unroll
        for (int mf = 0; mf < 8; ++mf) {
#pragma unroll
          for (int j = 0; j < 4; ++j)
            fl[wbase + (mf * 16 + g4 + j) * 36 + q * 16 + c_lane] = acc[mf][nf][j];
        }
      }
      int colbase = nt * BN + wn * 64 + p * 32;
      f32x4 bv4 = *reinterpret_cast<const f32x4*>(&bias[colbase + c4]);
      size_t rowabs0 = (size_t)mt * BM + wm * 128 + r8;
#pragma unroll
      for (int it = 0; it < 16; ++it) {
        f32x4 v = *reinterpret_cast<const f32x4*>(&fl[wbase + (it * 8 + r8) * 36 + c4]);
        v += bv4;
        *reinterpret_cast<f32x4*>(&out[(rowabs0 + it * 8) * kDout + colbase + c4]) = v;
      }
    }
  }
}

extern "C" void kernel_launch(void* const* d_in, const int* in_sizes, int n_in,
                              void* d_out, int out_size, void* d_ws, size_t ws_size,
                              hipStream_t stream) {
  const float* h    = (const float*)d_in[0];   // [32,1024,1024] f32
  const int*   aids = (const int*)d_in[1];     // [32] i32
  const float* W    = (const float*)d_in[2];   // [1024,4096] f32
  const float* bias = (const float*)d_in[3];   // [4096] f32
  const float* la   = (const float*)d_in[4];   // [8,1024,16] f32
  const float* lb   = (const float*)d_in[5];   // [8,16,4096] f32
  float* out = (float*)d_out;                  // [32,1024,4096] f32

  unsigned short* Abf  = (unsigned short*)d_ws;
  unsigned short* Weff = Abf + (size_t)kM * kDin;

  prep_kernel<<<kPrepBlocks, 256, 0, stream>>>(h, Abf, W, la, lb, Weff);
  gemm256_kernel<<<NWG2, 512, 0, stream>>>(Abf, Weff, bias, aids, out);
}